// Round 5
// baseline (955.805 us; speedup 1.0000x reference)
//
#include <hip/hip_runtime.h>

// x:   (2,4,8,8,8,96,96) fp32   strides: b 18874368, ci 4718592, cd 589824, t 73728, d 9216, h 96, w 1
// W:   (9,4,4,3,3,3)     fp32   strides: ij 432, o 108, ci 27, kd 9, kh 3, kw 1
// b:   (9,4)             fp32
// out: (2,4,6,6,8,96,96) fp32   strides: b 10616832, o 2654208, c 442368, t 73728, d 9216, h 96, w 1
//
// Block = (b,c,t,d, h-tile 32). 256 thr: wt=tid&7 (12-wide w tile), hr=tid>>3.
// Per (ci,i,j): stage 3 d-planes x 34 h-rows x 96 w into LDS (coalesced float4,
// row stride 104, w=0 at col 4 so all vector ops are 16B aligned; halo cols
// 3/100 pre-zeroed once). Compute taps = 2x ds_read_b32 + 3x ds_read_b128,
// bank-uniform. Weights pre-transposed into d_ws by a prologue kernel and read
// with fully-uniform indices -> s_load into SGPRs (scalar pipe, no LDS).

#define BLOCK 256

__global__ void wtr_kernel(const float* __restrict__ Wg, float* __restrict__ ws) {
    int k = blockIdx.x * 256 + threadIdx.x;   // 0..3887
    if (k >= 3888) return;
    // ws layout: [ci][ij][q=kd*3+kh][kw][o]  (index = ci*972+ij*108+q*12+kw*4+o)
    int o  = k & 3;   int r = k >> 2;
    int kw = r % 3;   r /= 3;
    int q  = r % 9;   r /= 9;
    int ij = r % 9;   int ci = r / 9;
    int kd = q / 3, kh = q % 3;
    ws[k] = Wg[ij*432 + o*108 + ci*27 + kd*9 + kh*3 + kw];
}

__global__ __launch_bounds__(256, 3) void conv5d_kernel(
    const float* __restrict__ xg,
    const float* __restrict__ wsg,   // transposed weights in d_ws
    const float* __restrict__ bg,
    float* __restrict__ outg)
{
    __shared__ float xs[102 * 104];  // [pl(3)*34 + hr(34)][col(104)]

    // zero the w-halo columns once (w=-1 at col 3, w=96 at col 100);
    // staging only writes cols 4..99, so these stay zero.
    for (int r = threadIdx.x; r < 102; r += BLOCK) {
        xs[r*104 + 3]   = 0.f;
        xs[r*104 + 100] = 0.f;
    }

    // 1728 blocks = 72 (b,c,t) slabs x 8 d x 3 h-tiles. XCD swizzle: bi&7.
    int bi   = blockIdx.x;
    int xcd  = bi & 7;
    int g    = bi >> 3;              // 0..215
    int slab = xcd*9 + g/24;         // 0..71
    int r2   = g % 24;
    int d    = r2 / 3;               // 0..7
    int ht   = r2 % 3;               // 0..2
    int b    = slab / 36;
    int ct   = slab % 36;
    int c    = ct / 6;
    int t    = ct % 6;
    int h0   = ht * 32;

    int wt = threadIdx.x & 7;        // w0 = 12*wt
    int hr = threadIdx.x >> 3;       // 0..31

    float acc[4][12] = {};

    #pragma unroll 1
    for (int ci = 0; ci < 4; ++ci) {
        #pragma unroll 1
        for (int i = 0; i < 3; ++i) {
            #pragma unroll 1
            for (int j = 0; j < 3; ++j) {
                const float* xp = xg + (size_t)b*18874368 + (size_t)ci*4718592
                                     + (size_t)(c + i)*589824
                                     + (size_t)(t + j)*73728;

                __syncthreads();   // previous iter's readers done

                // stage: 102 rows x 24 float4, coalesced; OOB rows -> 0
                for (int u = threadIdx.x; u < 2448; u += BLOCK) {
                    int row = u / 24;          // 0..101
                    int q   = u % 24;
                    int pl  = row / 34;        // 0..2
                    int hr2 = row % 34;        // 0..33
                    int dd  = d + pl - 1;
                    int hh  = h0 + hr2 - 1;
                    bool val = ((unsigned)dd < 8u) && ((unsigned)hh < 96u);
                    float4 v = *(const float4*)(xp + (val ? dd : 0)*9216
                                                   + (val ? hh : 0)*96 + q*4);
                    if (!val) v = make_float4(0.f, 0.f, 0.f, 0.f);
                    *(float4*)&xs[row*104 + 4 + q*4] = v;
                }

                __syncthreads();

                // compute: 9 rows x 3 kw x 12 w x 4 o = 1296 FMAs
                const float* wb = wsg + (ci*9 + i*3 + j) * 108;  // uniform base
                #pragma unroll
                for (int pl = 0; pl < 3; ++pl) {
                    #pragma unroll
                    for (int kh = 0; kh < 3; ++kh) {
                        const float* xr = &xs[(pl*34 + hr + kh)*104 + 12*wt + 3];
                        float4 A = *(const float4*)(xr + 1);
                        float4 B = *(const float4*)(xr + 5);
                        float4 C = *(const float4*)(xr + 9);
                        float xv[14];
                        xv[0]  = xr[0];
                        xv[1]  = A.x; xv[2]  = A.y; xv[3]  = A.z; xv[4]  = A.w;
                        xv[5]  = B.x; xv[6]  = B.y; xv[7]  = B.z; xv[8]  = B.w;
                        xv[9]  = C.x; xv[10] = C.y; xv[11] = C.z; xv[12] = C.w;
                        xv[13] = xr[13];
                        const float* wr = wb + (pl*3 + kh)*12;   // uniform
                        float4 wk0 = ((const float4*)wr)[0];
                        float4 wk1 = ((const float4*)wr)[1];
                        float4 wk2 = ((const float4*)wr)[2];
                        #pragma unroll
                        for (int v = 0; v < 12; ++v) {
                            float a = xv[v], bb = xv[v+1], cc = xv[v+2];
                            acc[0][v] = fmaf(a,  wk0.x, acc[0][v]);
                            acc[1][v] = fmaf(a,  wk0.y, acc[1][v]);
                            acc[2][v] = fmaf(a,  wk0.z, acc[2][v]);
                            acc[3][v] = fmaf(a,  wk0.w, acc[3][v]);
                            acc[0][v] = fmaf(bb, wk1.x, acc[0][v]);
                            acc[1][v] = fmaf(bb, wk1.y, acc[1][v]);
                            acc[2][v] = fmaf(bb, wk1.z, acc[2][v]);
                            acc[3][v] = fmaf(bb, wk1.w, acc[3][v]);
                            acc[0][v] = fmaf(cc, wk2.x, acc[0][v]);
                            acc[1][v] = fmaf(cc, wk2.y, acc[1][v]);
                            acc[2][v] = fmaf(cc, wk2.z, acc[2][v]);
                            acc[3][v] = fmaf(cc, wk2.w, acc[3][v]);
                        }
                    }
                }
            }
        }
    }

    // mean bias over the 9 (i,j) taps
    float mb[4];
    #pragma unroll
    for (int o = 0; o < 4; ++o) {
        float s = 0.f;
        #pragma unroll
        for (int ij = 0; ij < 9; ++ij) s += bg[ij*4 + o];
        mb[o] = s * (1.0f / 9.0f);
    }

    const float inv9 = 1.0f / 9.0f;
    size_t obase = (size_t)b*10616832 + (size_t)c*442368 + (size_t)t*73728
                 + (size_t)d*9216 + (size_t)(h0 + hr)*96 + 12*wt;
    #pragma unroll
    for (int o = 0; o < 4; ++o) {
        float* op = outg + obase + (size_t)o*2654208;
        #pragma unroll
        for (int v4 = 0; v4 < 3; ++v4) {
            float4 st;
            st.x = acc[o][4*v4+0]*inv9 + mb[o];
            st.y = acc[o][4*v4+1]*inv9 + mb[o];
            st.z = acc[o][4*v4+2]*inv9 + mb[o];
            st.w = acc[o][4*v4+3]*inv9 + mb[o];
            *(float4*)(op + 4*v4) = st;
        }
    }
}

extern "C" void kernel_launch(void* const* d_in, const int* in_sizes, int n_in,
                              void* d_out, int out_size, void* d_ws, size_t ws_size,
                              hipStream_t stream) {
    const float* x = (const float*)d_in[0];
    const float* W = (const float*)d_in[1];
    const float* b = (const float*)d_in[2];
    float* out = (float*)d_out;
    float* ws  = (float*)d_ws;
    wtr_kernel<<<16, 256, 0, stream>>>(W, ws);
    conv5d_kernel<<<1728, BLOCK, 0, stream>>>(x, ws, b, out);
}